// Round 5
// baseline (85.077 us; speedup 1.0000x reference)
//
#include <hip/hip_runtime.h>

// RegularizationLoss: out = (1/2e6) * sum over 4M consecutive 3x3 matrices M
// of ||M M^T - I||_F^2.  Input (2000000,6,3) f32 = 144 MB. Memory-bound.
//
// Fused single kernel:
//  - per-WAVE LDS tiles (no __syncthreads in main loop): each wave stages
//    256 matrices (576 float4, 9 KB) with unit-stride float4 rounds, then
//    computes from LDS (9-float odd stride -> bank-conflict-free).
//  - 4,000,000 matrices = 15625 wave-tiles exactly -> no guards, no tail.
//  - last-block-done reduction over per-block partials in FIXED index order
//    -> bit-deterministic; counter zeroed per launch via hipMemsetAsync node.

#define NTHR 256
#define NBLK 977
#define NWAVES 4                       // waves per block
#define TOTAL_WAVES (NBLK * NWAVES)    // 3908
#define WT_F4 576                      // float4 per wave-tile (256 matrices)
#define WT_FLOATS 2304                 // floats per wave-tile (9216 B)

__global__ __launch_bounds__(NTHR) void reg_loss_fused(
    const float4* __restrict__ in4,
    float* __restrict__ partial,       // d_ws + 1024: NBLK floats
    unsigned int* __restrict__ counter,// d_ws + 0
    float* __restrict__ out,
    int nwtiles, float invN) {
    __shared__ float lds[NWAVES][WT_FLOATS];
    __shared__ float wsum[NWAVES];
    __shared__ int is_last;

    const int t = threadIdx.x;
    const int lane = t & 63;
    const int wid = t >> 6;
    const int gw = blockIdx.x * NWAVES + wid;   // global wave id
    float acc = 0.0f;

    for (int T = gw; T < nwtiles; T += TOTAL_WAVES) {
        const long long b4 = (long long)T * WT_F4;
        // stage: 9 rounds, 64 lanes x 16 B unit-stride (1 KB per instruction)
        #pragma unroll
        for (int k = 0; k < 9; ++k) {
            *(float4*)&lds[wid][4 * (64 * k + lane)] = in4[b4 + 64 * k + lane];
        }
        // wave-private region: no block barrier needed, just drain DS writes
        __builtin_amdgcn_wave_barrier();
        asm volatile("s_waitcnt lgkmcnt(0)" ::: "memory");

        #pragma unroll
        for (int j = 0; j < 4; ++j) {
            const float* M = &lds[wid][9 * (64 * j + lane)];
            float a00 = M[0]*M[0] + M[1]*M[1] + M[2]*M[2] - 1.0f;
            float a11 = M[3]*M[3] + M[4]*M[4] + M[5]*M[5] - 1.0f;
            float a22 = M[6]*M[6] + M[7]*M[7] + M[8]*M[8] - 1.0f;
            float a01 = M[0]*M[3] + M[1]*M[4] + M[2]*M[5];
            float a02 = M[0]*M[6] + M[1]*M[7] + M[2]*M[8];
            float a12 = M[3]*M[6] + M[4]*M[7] + M[5]*M[8];
            acc += a00*a00 + a11*a11 + a22*a22
                 + 2.0f * (a01*a01 + a02*a02 + a12*a12);
        }
        __builtin_amdgcn_wave_barrier();
    }

    // wave64 reduction -> per-block partial
    #pragma unroll
    for (int off = 32; off > 0; off >>= 1) acc += __shfl_down(acc, off, 64);
    if (lane == 0) wsum[wid] = acc;
    __syncthreads();
    if (t == 0) {
        float s = wsum[0] + wsum[1] + wsum[2] + wsum[3];
        __hip_atomic_store(&partial[blockIdx.x], s,
                           __ATOMIC_RELEASE, __HIP_MEMORY_SCOPE_AGENT);
        unsigned old = __hip_atomic_fetch_add(counter, 1u,
                           __ATOMIC_ACQ_REL, __HIP_MEMORY_SCOPE_AGENT);
        is_last = (old == (unsigned)(gridDim.x - 1)) ? 1 : 0;
    }
    __syncthreads();

    if (is_last) {  // block-uniform
        __threadfence();  // device-scope acquire-ish fence before reading partials
        float a2 = 0.0f;
        for (int i = t; i < NBLK; i += NTHR) {
            a2 += __hip_atomic_load(&partial[i],
                      __ATOMIC_RELAXED, __HIP_MEMORY_SCOPE_AGENT);
        }
        #pragma unroll
        for (int off = 32; off > 0; off >>= 1) a2 += __shfl_down(a2, off, 64);
        if (lane == 0) wsum[wid] = a2;
        __syncthreads();
        if (t == 0) out[0] = (wsum[0] + wsum[1] + wsum[2] + wsum[3]) * invN;
    }
}

extern "C" void kernel_launch(void* const* d_in, const int* in_sizes, int n_in,
                              void* d_out, int out_size, void* d_ws, size_t ws_size,
                              hipStream_t stream) {
    const float* in = (const float*)d_in[0];
    float* out = (float*)d_out;
    unsigned int* counter = (unsigned int*)d_ws;
    float* partial = (float*)((char*)d_ws + 1024);

    const int total_floats = in_sizes[0];        // 36,000,000
    const int nbatch = total_floats / 18;        // 2,000,000
    const int nwtiles = total_floats / WT_FLOATS;// 15,625 exact (no tail)

    (void)hipMemsetAsync(counter, 0, sizeof(unsigned int), stream);
    reg_loss_fused<<<NBLK, NTHR, 0, stream>>>(
        (const float4*)in, partial, counter, out, nwtiles, 1.0f / (float)nbatch);
}